// Round 7
// baseline (641.566 us; speedup 1.0000x reference)
//
#include <hip/hip_runtime.h>

#define N_TOK 8192
#define DIM   2048
#define HID   2048
#define NE    8
#define NKT   (DIM / 64)

typedef unsigned short u16;
typedef __attribute__((ext_vector_type(4))) float f4v;
typedef __attribute__((ext_vector_type(8))) short s8v;
typedef __attribute__((ext_vector_type(4))) unsigned short us4;

__device__ __forceinline__ u16 f2bf(float f) {
  union { float f; unsigned int u; } c; c.f = f;
  unsigned int u = c.u;
  unsigned int r = (u + 0x7FFFu + ((u >> 16) & 1u)) >> 16;
  return (u16)r;
}

// ---------------- gating: logits -> softmax -> top2 (NO atomics) ----------------
__global__ __launch_bounds__(256) void gating_kernel(
    const float* __restrict__ x, const float* __restrict__ Wg,
    const float* __restrict__ bg, int* __restrict__ sel,
    float* __restrict__ wslot)
{
  __shared__ float wg_lds[NE][DIM];   // 64 KB
  #pragma unroll
  for (int i = 0; i < 16; ++i) {
    int f = threadIdx.x + 256 * i;          // float4 index 0..4095
    int d = f >> 1, ep = (f & 1) * 4;
    float4 w = reinterpret_cast<const float4*>(Wg)[f];
    wg_lds[ep + 0][d] = w.x; wg_lds[ep + 1][d] = w.y;
    wg_lds[ep + 2][d] = w.z; wg_lds[ep + 3][d] = w.w;
  }
  __syncthreads();

  int wave = threadIdx.x >> 6, lane = threadIdx.x & 63;
  #pragma unroll 2
  for (int j = 0; j < 4; ++j) {
    int n = blockIdx.x * 16 + wave * 4 + j;
    const float4* x4 = reinterpret_cast<const float4*>(x + (size_t)n * DIM);
    float acc[NE] = {0.f,0.f,0.f,0.f,0.f,0.f,0.f,0.f};
    #pragma unroll
    for (int i = 0; i < 8; ++i) {
      int d4 = lane + 64 * i;
      float4 xv = x4[d4];
      #pragma unroll
      for (int e = 0; e < NE; ++e) {
        float4 w = *reinterpret_cast<const float4*>(&wg_lds[e][d4 * 4]);
        acc[e] += xv.x * w.x + xv.y * w.y + xv.z * w.z + xv.w * w.w;
      }
    }
    #pragma unroll
    for (int e = 0; e < NE; ++e)
      #pragma unroll
      for (int off = 32; off; off >>= 1)
        acc[e] += __shfl_xor(acc[e], off);

    if (lane == 0) {
      float m = -1e30f;
      #pragma unroll
      for (int e = 0; e < NE; ++e) { acc[e] += bg[e]; m = fmaxf(m, acc[e]); }
      float p[NE]; float s = 0.f;
      #pragma unroll
      for (int e = 0; e < NE; ++e) { p[e] = expf(acc[e] - m); s += p[e]; }
      float inv = 1.0f / s;
      int e1 = 0; float v1 = p[0];
      #pragma unroll
      for (int e = 1; e < NE; ++e) if (p[e] > v1) { v1 = p[e]; e1 = e; }
      int e2 = -1; float v2 = -1.f;
      #pragma unroll
      for (int e = 0; e < NE; ++e) if (e != e1 && p[e] > v2) { v2 = p[e]; e2 = e; }
      sel[n] = e1 | (e2 << 4);
      wslot[n] = v1 * inv;
      wslot[N_TOK + n] = v2 * inv;
    }
  }
}

// ---------------- build per-(slot,expert) token lists: deterministic compaction ----------------
__global__ __launch_bounds__(256) void build_lists_kernel(
    const int* __restrict__ sel, int* __restrict__ counts, int* __restrict__ lists)
{
  __shared__ int wsum[4];
  __shared__ int runbase;
  int b = blockIdx.x;           // 0..15: slot = b>>3, expert = b&7
  int s = b >> 3, e = b & 7;
  int t = threadIdx.x, lane = t & 63, wave = t >> 6;
  if (t == 0) runbase = 0;
  __syncthreads();
  int* listp = lists + (size_t)b * N_TOK;
  for (int base = 0; base < N_TOK; base += 256) {
    int n = base + t;
    int sv = sel[n];
    int field = s ? (sv >> 4) : (sv & 15);
    bool p = (field == e);
    unsigned long long mask = __ballot(p);
    int rank = __popcll(mask & ((1ull << lane) - 1ull));
    int wtot = __popcll(mask);
    if (lane == 0) wsum[wave] = wtot;
    __syncthreads();
    int wbase = 0;
    #pragma unroll
    for (int w = 0; w < 4; ++w) wbase += (w < wave) ? wsum[w] : 0;
    int tot = wsum[0] + wsum[1] + wsum[2] + wsum[3];
    if (p) listp[runbase + wbase + rank] = n;
    __syncthreads();
    if (t == 0) runbase += tot;
    __syncthreads();
  }
  if (t == 0) counts[b] = runbase;
}

// ---------------- build compact tile descriptors ----------------
__global__ void build_desc_kernel(const int* __restrict__ counts,
                                  int* __restrict__ gfirst, int* __restrict__ desc)
{
  if (threadIdx.x == 0 && blockIdx.x == 0) {
    for (int s = 0; s < 2; ++s) {
      int tc = 0;
      for (int e = 0; e < NE; ++e) {
        gfirst[s * 9 + e] = tc;
        int nt = (counts[s * NE + e] + 127) >> 7;
        for (int i = 0; i < nt; ++i) desc[s * 71 + tc++] = (e << 8) | i;
      }
      gfirst[s * 9 + 8] = tc;
    }
  }
}

// ---------------- GEMM core ----------------
__device__ __forceinline__ void mma_step(const u16* A_lds, const u16* B_lds,
                                         int lane, int wm, int wn, f4v acc[4][4])
{
  int lrow = lane & 15, lkg = lane >> 4;
  #pragma unroll
  for (int kk2 = 0; kk2 < 2; ++kk2) {
    s8v a[4], b[4];
    unsigned int koff = (unsigned int)(kk2 * 64 + lkg * 16);
    #pragma unroll
    for (int i = 0; i < 4; ++i) {
      unsigned int arow = (unsigned int)(wm + i * 16 + lrow);
      a[i] = *reinterpret_cast<const s8v*>(
          reinterpret_cast<const char*>(A_lds) + ((arow * 128u + koff) ^ ((arow & 7u) << 4)));
      unsigned int brow = (unsigned int)(wn + i * 16 + lrow);
      b[i] = *reinterpret_cast<const s8v*>(
          reinterpret_cast<const char*>(B_lds) + ((brow * 128u + koff) ^ ((brow & 7u) << 4)));
    }
    #pragma unroll
    for (int mi = 0; mi < 4; ++mi)
      #pragma unroll
      for (int ni = 0; ni < 4; ++ni)
        acc[mi][ni] = __builtin_amdgcn_mfma_f32_16x16x32_bf16(a[mi], b[ni], acc[mi][ni], 0, 0, 0);
  }
}

// R3 structure, request-count-optimized staging:
//   A: 8 x float4 gather (1KB/request) + 8 x 8B LDS writes   [unchanged]
//   B: 8 x float4 h-major (1KB/request) + in-reg transpose + 4 x ds_write_b128
// (was: 32 scalar 4B-per-lane loads = 256B/request -> request-rate bound @~20cyc/req)
template <int PHASE>
__global__ __launch_bounds__(256, 3) void moe_gemm_f32(
    const float* __restrict__ xf, const float* __restrict__ Wef,
    const float* __restrict__ be, const int* __restrict__ counts,
    const int* __restrict__ gfirst, const int* __restrict__ desc,
    const int* __restrict__ lists, const float* __restrict__ wslot,
    float* __restrict__ out)
{
  __shared__ __align__(16) u16 A_lds[128 * 64];
  __shared__ __align__(16) u16 B_lds[128 * 64];
  __shared__ int   tok_lds[128];
  __shared__ float wgt_lds[128];

  const int ntile = blockIdx.x;          // 0..15 (fastest: A-tile shared across concurrent blocks)
  const int idx   = blockIdx.y;          // 0..70
  if (idx >= gfirst[PHASE * 9 + 8]) return;
  const int d  = desc[PHASE * 71 + idx];
  const int e  = d >> 8;
  const int mt = d & 255;
  const int cnt = counts[PHASE * NE + e];

  const int t = threadIdx.x;
  if (t < 128) {
    int r = mt * 128 + t;
    int rc = (r < cnt) ? r : (cnt - 1);
    int tok = lists[(PHASE * NE + e) * N_TOK + rc];
    tok_lds[t] = tok;
    wgt_lds[t] = wslot[PHASE * N_TOK + tok];
  }
  __syncthreads();

  const int lane = t & 63, wid = t >> 6;
  const int wm = (wid & 1) * 64, wn = (wid >> 1) * 64;

  f4v acc[4][4];
  f4v zero = {0.f, 0.f, 0.f, 0.f};
  #pragma unroll
  for (int mi = 0; mi < 4; ++mi)
    #pragma unroll
    for (int ni = 0; ni < 4; ++ni) acc[mi][ni] = zero;

  const float* wef = Wef + (size_t)e * DIM * HID;

  // A gather pointers: thread covers 8 (row, 16B-chunk) slots
  const float* ap[8]; unsigned int ab[8];
  #pragma unroll
  for (int i = 0; i < 8; ++i) {
    int flat = t + 256 * i;             // 0..2047
    int row = flat >> 4, c4 = flat & 15;
    ap[i] = xf + (size_t)tok_lds[row] * DIM + c4 * 4;
    ab[i] = ((unsigned int)(row * 128 + c4 * 8)) ^ (((unsigned int)row & 7u) << 4);
  }

  // B h-major: thread t -> h-chunk hc = t&31 (h = hc*4), k-group kg = t>>5 (k = kg*8 + j)
  const int hc = t & 31, kg = t >> 5;
  const float* bsrc = wef + (size_t)kg * 8 * HID + ntile * 128 + hc * 4;

  #pragma unroll 1
  for (int kt = 0; kt < NKT; ++kt) {
    // ---- issue all 16 x 1KB load requests ----
    float4 av[8];
    #pragma unroll
    for (int i = 0; i < 8; ++i)
      av[i] = *reinterpret_cast<const float4*>(ap[i] + kt * 64);
    float4 bq[8];
    const float* bk = bsrc + (size_t)kt * 64 * HID;
    #pragma unroll
    for (int j = 0; j < 8; ++j)
      bq[j] = *reinterpret_cast<const float4*>(bk + (size_t)j * HID);

    // ---- A -> LDS (same layout/swizzle as always) ----
    #pragma unroll
    for (int i = 0; i < 8; ++i) {
      us4 u = {f2bf(av[i].x), f2bf(av[i].y), f2bf(av[i].z), f2bf(av[i].w)};
      *reinterpret_cast<us4*>(reinterpret_cast<char*>(A_lds) + ab[i]) = u;
    }
    // ---- B transpose in regs -> 4 x ds_write_b128 ----
    #pragma unroll
    for (int c = 0; c < 4; ++c) {
      float cv[8] = {bq[0][c], bq[1][c], bq[2][c], bq[3][c],
                     bq[4][c], bq[5][c], bq[6][c], bq[7][c]};
      s8v bw;
      #pragma unroll
      for (int j = 0; j < 8; ++j) bw[j] = (short)f2bf(cv[j]);
      unsigned int brow = (unsigned int)(hc * 4 + c);
      unsigned int byte = (brow * 128u + (unsigned int)kg * 16u) ^ ((brow & 7u) << 4);
      *reinterpret_cast<s8v*>(reinterpret_cast<char*>(B_lds) + byte) = bw;
    }
    __syncthreads();
    mma_step(A_lds, B_lds, lane, wm, wn, acc);
    __syncthreads();
  }

  // epilogue: D row=(lane>>4)*4+q (A/m), col=lane&15 (B/n)  [m89-verified]
  const float* bev = be + (size_t)e * HID + ntile * 128;
  #pragma unroll
  for (int ni = 0; ni < 4; ++ni) {
    int col = wn + ni * 16 + (lane & 15);
    float bevv = bev[col];
    #pragma unroll
    for (int mi = 0; mi < 4; ++mi) {
      #pragma unroll
      for (int q = 0; q < 4; ++q) {
        int row = wm + mi * 16 + (lane >> 4) * 4 + q;
        if (mt * 128 + row < cnt) {
          int tok = tok_lds[row];
          float w = wgt_lds[row];
          float v = w * (acc[mi][ni][q] + bevv);
          float* o = out + (size_t)tok * HID + ntile * 128 + col;
          if (PHASE == 0) *o = v; else *o += v;
        }
      }
    }
  }
}

// ---------------- host ----------------
extern "C" void kernel_launch(void* const* d_in, const int* in_sizes, int n_in,
                              void* d_out, int out_size, void* d_ws, size_t ws_size,
                              hipStream_t stream) {
  const float* x  = (const float*)d_in[0];
  const float* Wg = (const float*)d_in[1];
  const float* bg = (const float*)d_in[2];
  const float* We = (const float*)d_in[3];
  const float* be = (const float*)d_in[4];
  float* out = (float*)d_out;
  char* ws = (char*)d_ws;

  int*   counts = (int*)ws;                         // 16 ints @0
  int*   gfirst = (int*)(ws + 64);                  // 18 ints
  int*   desc   = (int*)(ws + 256);                 // 142 ints
  int*   sel    = (int*)(ws + 1024);                // 8192 ints
  float* wslot  = (float*)(ws + 33792);             // 16384 f32
  int*   lists  = (int*)(ws + 99328);               // 2*8*8192 ints -> end 623616

  hipLaunchKernelGGL(gating_kernel, dim3(512), dim3(256), 0, stream,
                     x, Wg, bg, sel, wslot);
  hipLaunchKernelGGL(build_lists_kernel, dim3(16), dim3(256), 0, stream,
                     sel, counts, lists);
  hipLaunchKernelGGL(build_desc_kernel, dim3(1), dim3(64), 0, stream,
                     counts, gfirst, desc);

  dim3 ggrid(16, 71);   // x = ntile fastest: R3 L2 locality
  hipLaunchKernelGGL((moe_gemm_f32<0>), ggrid, dim3(256), 0, stream,
                     x, We, be, counts, gfirst, desc, lists, wslot, out);
  hipLaunchKernelGGL((moe_gemm_f32<1>), ggrid, dim3(256), 0, stream,
                     x, We, be, counts, gfirst, desc, lists, wslot, out);
}

// Round 8
// 542.482 us; speedup vs baseline: 1.1826x; 1.1826x over previous
//
#include <hip/hip_runtime.h>

#define N_TOK 8192
#define DIM   2048
#define HID   2048
#define NE    8
#define NKT   (DIM / 64)

typedef unsigned short u16;
typedef __attribute__((ext_vector_type(4))) float f4v;
typedef __attribute__((ext_vector_type(8))) short s8v;

__device__ __forceinline__ unsigned int cvtpk(float lo, float hi) {
  unsigned int r;
  asm volatile("v_cvt_pk_bf16_f32 %0, %1, %2" : "=v"(r) : "v"(lo), "v"(hi));
  return r;
}

__device__ __forceinline__ void gll16(const void* g, void* l) {
  __builtin_amdgcn_global_load_lds(
      (const __attribute__((address_space(1))) void*)g,
      (__attribute__((address_space(3))) void*)l, 16, 0, 0);
}

// ---------------- gating: logits -> softmax -> top2 (NO atomics) ----------------
__global__ __launch_bounds__(256) void gating_kernel(
    const float* __restrict__ x, const float* __restrict__ Wg,
    const float* __restrict__ bg, int* __restrict__ sel,
    float* __restrict__ wslot)
{
  __shared__ float wg_lds[NE][DIM];   // 64 KB
  #pragma unroll
  for (int i = 0; i < 16; ++i) {
    int f = threadIdx.x + 256 * i;          // float4 index 0..4095
    int d = f >> 1, ep = (f & 1) * 4;
    float4 w = reinterpret_cast<const float4*>(Wg)[f];
    wg_lds[ep + 0][d] = w.x; wg_lds[ep + 1][d] = w.y;
    wg_lds[ep + 2][d] = w.z; wg_lds[ep + 3][d] = w.w;
  }
  __syncthreads();

  int wave = threadIdx.x >> 6, lane = threadIdx.x & 63;
  #pragma unroll 2
  for (int j = 0; j < 4; ++j) {
    int n = blockIdx.x * 16 + wave * 4 + j;
    const float4* x4 = reinterpret_cast<const float4*>(x + (size_t)n * DIM);
    float acc[NE] = {0.f,0.f,0.f,0.f,0.f,0.f,0.f,0.f};
    #pragma unroll
    for (int i = 0; i < 8; ++i) {
      int d4 = lane + 64 * i;
      float4 xv = x4[d4];
      #pragma unroll
      for (int e = 0; e < NE; ++e) {
        float4 w = *reinterpret_cast<const float4*>(&wg_lds[e][d4 * 4]);
        acc[e] += xv.x * w.x + xv.y * w.y + xv.z * w.z + xv.w * w.w;
      }
    }
    #pragma unroll
    for (int e = 0; e < NE; ++e)
      #pragma unroll
      for (int off = 32; off; off >>= 1)
        acc[e] += __shfl_xor(acc[e], off);

    if (lane == 0) {
      float m = -1e30f;
      #pragma unroll
      for (int e = 0; e < NE; ++e) { acc[e] += bg[e]; m = fmaxf(m, acc[e]); }
      float p[NE]; float s = 0.f;
      #pragma unroll
      for (int e = 0; e < NE; ++e) { p[e] = expf(acc[e] - m); s += p[e]; }
      float inv = 1.0f / s;
      int e1 = 0; float v1 = p[0];
      #pragma unroll
      for (int e = 1; e < NE; ++e) if (p[e] > v1) { v1 = p[e]; e1 = e; }
      int e2 = -1; float v2 = -1.f;
      #pragma unroll
      for (int e = 0; e < NE; ++e) if (e != e1 && p[e] > v2) { v2 = p[e]; e2 = e; }
      sel[n] = e1 | (e2 << 4);
      wslot[n] = v1 * inv;
      wslot[N_TOK + n] = v2 * inv;
    }
  }
}

// ---------------- build per-(slot,expert) token lists: deterministic compaction ----------------
__global__ __launch_bounds__(256) void build_lists_kernel(
    const int* __restrict__ sel, int* __restrict__ counts, int* __restrict__ lists)
{
  __shared__ int wsum[4];
  __shared__ int runbase;
  int b = blockIdx.x;           // 0..15: slot = b>>3, expert = b&7
  int s = b >> 3, e = b & 7;
  int t = threadIdx.x, lane = t & 63, wave = t >> 6;
  if (t == 0) runbase = 0;
  __syncthreads();
  int* listp = lists + (size_t)b * N_TOK;
  for (int base = 0; base < N_TOK; base += 256) {
    int n = base + t;
    int sv = sel[n];
    int field = s ? (sv >> 4) : (sv & 15);
    bool p = (field == e);
    unsigned long long mask = __ballot(p);
    int rank = __popcll(mask & ((1ull << lane) - 1ull));
    int wtot = __popcll(mask);
    if (lane == 0) wsum[wave] = wtot;
    __syncthreads();
    int wbase = 0;
    #pragma unroll
    for (int w = 0; w < 4; ++w) wbase += (w < wave) ? wsum[w] : 0;
    int tot = wsum[0] + wsum[1] + wsum[2] + wsum[3];
    if (p) listp[runbase + wbase + rank] = n;
    __syncthreads();
    if (t == 0) runbase += tot;
    __syncthreads();
  }
  if (t == 0) counts[b] = runbase;
}

// ---------------- build compact tile descriptors ----------------
__global__ void build_desc_kernel(const int* __restrict__ counts,
                                  int* __restrict__ gfirst, int* __restrict__ desc)
{
  if (threadIdx.x == 0 && blockIdx.x == 0) {
    for (int s = 0; s < 2; ++s) {
      int tc = 0;
      for (int e = 0; e < NE; ++e) {
        gfirst[s * 9 + e] = tc;
        int nt = (counts[s * NE + e] + 127) >> 7;
        for (int i = 0; i < nt; ++i) desc[s * 71 + tc++] = (e << 8) | i;
      }
      gfirst[s * 9 + 8] = tc;
    }
  }
}

// ---------------- GEMM core: A from f32 LDS (cvt_pk at frag load), B bf16 LDS ----------------
__device__ __forceinline__ void mma_step(const float* A_lds, const u16* B_lds,
                                         int lane, int wm, int wn, f4v acc[4][4])
{
  int lrow = lane & 15, lkg = lane >> 4;
  #pragma unroll
  for (int kk2 = 0; kk2 < 2; ++kk2) {
    s8v a[4], b[4];
    unsigned int koffB = (unsigned int)(kk2 * 64 + lkg * 16);    // bf16 bytes
    unsigned int koffA = (unsigned int)(kk2 * 128 + lkg * 32);   // f32 bytes
    #pragma unroll
    for (int i = 0; i < 4; ++i) {
      unsigned int arow = (unsigned int)(wm + i * 16 + lrow);
      unsigned int asw = (arow & 7u) << 4;
      const char* abase = reinterpret_cast<const char*>(A_lds) + arow * 256u;
      f4v lo = *reinterpret_cast<const f4v*>(abase + (koffA ^ asw));
      f4v hi = *reinterpret_cast<const f4v*>(abase + ((koffA + 16u) ^ asw));
      union { unsigned int w[4]; s8v v; } ua;
      ua.w[0] = cvtpk(lo[0], lo[1]); ua.w[1] = cvtpk(lo[2], lo[3]);
      ua.w[2] = cvtpk(hi[0], hi[1]); ua.w[3] = cvtpk(hi[2], hi[3]);
      a[i] = ua.v;
      unsigned int brow = (unsigned int)(wn + i * 16 + lrow);
      b[i] = *reinterpret_cast<const s8v*>(
          reinterpret_cast<const char*>(B_lds) + ((brow * 128u + koffB) ^ ((brow & 7u) << 4)));
    }
    #pragma unroll
    for (int mi = 0; mi < 4; ++mi)
      #pragma unroll
      for (int ni = 0; ni < 4; ++ni)
        acc[mi][ni] = __builtin_amdgcn_mfma_f32_16x16x32_bf16(a[mi], b[ni], acc[mi][ni], 0, 0, 0);
  }
}

// R3 structure; A staged via global_load_lds (f32, src pre-swizzled, fire-and-forget),
// B staged via R3 scalar column loads + v_cvt_pk_bf16_f32 pack.
template <int PHASE>
__global__ __launch_bounds__(256) void moe_gemm_f32(
    const float* __restrict__ xf, const float* __restrict__ Wef,
    const float* __restrict__ be, const int* __restrict__ counts,
    const int* __restrict__ gfirst, const int* __restrict__ desc,
    const int* __restrict__ lists, const float* __restrict__ wslot,
    float* __restrict__ out)
{
  __shared__ __align__(16) float A_lds[128 * 64];   // 32 KB f32, XOR-swizzled rows
  __shared__ __align__(16) u16   B_lds[128 * 64];   // 16 KB bf16 [n][k]
  __shared__ int   tok_lds[128];
  __shared__ float wgt_lds[128];

  const int ntile = blockIdx.x;          // 0..15 (fastest: A-tile shared across concurrent blocks)
  const int idx   = blockIdx.y;          // 0..70
  if (idx >= gfirst[PHASE * 9 + 8]) return;
  const int d  = desc[PHASE * 71 + idx];
  const int e  = d >> 8;
  const int mt = d & 255;
  const int cnt = counts[PHASE * NE + e];

  const int t = threadIdx.x;
  if (t < 128) {
    int r = mt * 128 + t;
    int rc = (r < cnt) ? r : (cnt - 1);
    int tok = lists[(PHASE * NE + e) * N_TOK + rc];
    tok_lds[t] = tok;
    wgt_lds[t] = wslot[PHASE * N_TOK + tok];
  }
  __syncthreads();

  const int lane = t & 63, wid = t >> 6;
  const int wm = (wid & 1) * 64, wn = (wid >> 1) * 64;

  f4v acc[4][4];
  f4v zero = {0.f, 0.f, 0.f, 0.f};
  #pragma unroll
  for (int mi = 0; mi < 4; ++mi)
    #pragma unroll
    for (int ni = 0; ni < 4; ++ni) acc[mi][ni] = zero;

  const float* wef = Wef + (size_t)e * DIM * HID;

  // A gll16: instr i covers rows wid*32+i*4 .. +3 (lane>>4 picks row, lane&15 the 16B chunk).
  // LDS dest linear; global source pre-swizzled by ((row&7)<<4) within the 256B row-slab.
  const char* ag[8]; char* ad[8];
  #pragma unroll
  for (int i = 0; i < 8; ++i) {
    int r = wid * 32 + i * 4 + (lane >> 4);
    int tok = tok_lds[r];
    ag[i] = reinterpret_cast<const char*>(xf + (size_t)tok * DIM)
          + ((((unsigned int)(lane & 15)) * 16u) ^ (((unsigned int)r & 7u) << 4));
    ad[i] = reinterpret_cast<char*>(A_lds) + (wid * 32 + i * 4) * 256;
  }
  // B scalar column loads (R3 path)
  const int bn = t & 127, bh = t >> 7;
  const float* bp0 = wef + (size_t)(bh * 32) * HID + ntile * 128 + bn;
  const unsigned int nswz = ((unsigned int)(bn & 7)) << 4;

  #pragma unroll 1
  for (int kt = 0; kt < NKT; ++kt) {
    // A: fire-and-forget direct-to-LDS (drained by the barrier)
    #pragma unroll
    for (int i = 0; i < 8; ++i)
      gll16(ag[i] + kt * 256, ad[i]);
    // B: 32 scalar loads -> cvt_pk -> 8B stores
    const float* bpk = bp0 + (size_t)kt * 64 * HID;
    float bv[32];
    #pragma unroll
    for (int kb = 0; kb < 8; ++kb)
      #pragma unroll
      for (int r = 0; r < 4; ++r)
        bv[kb * 4 + r] = bpk[(size_t)(kb * 4 + r) * HID];
    #pragma unroll
    for (int kb = 0; kb < 8; ++kb) {
      uint2 w;
      w.x = cvtpk(bv[kb * 4 + 0], bv[kb * 4 + 1]);
      w.y = cvtpk(bv[kb * 4 + 2], bv[kb * 4 + 3]);
      unsigned int byte = ((unsigned int)(bn * 128 + bh * 64 + kb * 8)) ^ nswz;
      *reinterpret_cast<uint2*>(reinterpret_cast<char*>(B_lds) + byte) = w;
    }
    __syncthreads();
    mma_step(A_lds, B_lds, lane, wm, wn, acc);
    __syncthreads();
  }

  // epilogue: D row=(lane>>4)*4+q (A/m), col=lane&15 (B/n)  [m89-verified]
  const float* bev = be + (size_t)e * HID + ntile * 128;
  #pragma unroll
  for (int ni = 0; ni < 4; ++ni) {
    int col = wn + ni * 16 + (lane & 15);
    float bevv = bev[col];
    #pragma unroll
    for (int mi = 0; mi < 4; ++mi) {
      #pragma unroll
      for (int q = 0; q < 4; ++q) {
        int row = wm + mi * 16 + (lane >> 4) * 4 + q;
        if (mt * 128 + row < cnt) {
          int tok = tok_lds[row];
          float w = wgt_lds[row];
          float v = w * (acc[mi][ni][q] + bevv);
          float* o = out + (size_t)tok * HID + ntile * 128 + col;
          if (PHASE == 0) *o = v; else *o += v;
        }
      }
    }
  }
}

// ---------------- host ----------------
extern "C" void kernel_launch(void* const* d_in, const int* in_sizes, int n_in,
                              void* d_out, int out_size, void* d_ws, size_t ws_size,
                              hipStream_t stream) {
  const float* x  = (const float*)d_in[0];
  const float* Wg = (const float*)d_in[1];
  const float* bg = (const float*)d_in[2];
  const float* We = (const float*)d_in[3];
  const float* be = (const float*)d_in[4];
  float* out = (float*)d_out;
  char* ws = (char*)d_ws;

  int*   counts = (int*)ws;                         // 16 ints @0
  int*   gfirst = (int*)(ws + 64);                  // 18 ints
  int*   desc   = (int*)(ws + 256);                 // 142 ints
  int*   sel    = (int*)(ws + 1024);                // 8192 ints
  float* wslot  = (float*)(ws + 33792);             // 16384 f32
  int*   lists  = (int*)(ws + 99328);               // 2*8*8192 ints -> end 623616

  hipLaunchKernelGGL(gating_kernel, dim3(512), dim3(256), 0, stream,
                     x, Wg, bg, sel, wslot);
  hipLaunchKernelGGL(build_lists_kernel, dim3(16), dim3(256), 0, stream,
                     sel, counts, lists);
  hipLaunchKernelGGL(build_desc_kernel, dim3(1), dim3(64), 0, stream,
                     counts, gfirst, desc);

  dim3 ggrid(16, 71);   // x = ntile fastest: R3 L2 locality
  hipLaunchKernelGGL((moe_gemm_f32<0>), ggrid, dim3(256), 0, stream,
                     x, We, be, counts, gfirst, desc, lists, wslot, out);
  hipLaunchKernelGGL((moe_gemm_f32<1>), ggrid, dim3(256), 0, stream,
                     x, We, be, counts, gfirst, desc, lists, wslot, out);
}

// Round 9
// 449.905 us; speedup vs baseline: 1.4260x; 1.2058x over previous
//
#include <hip/hip_runtime.h>

#define N_TOK 8192
#define DIM   2048
#define HID   2048
#define NE    8
#define NKT   (DIM / 64)

typedef unsigned short u16;
typedef __attribute__((ext_vector_type(4))) float f4v;
typedef __attribute__((ext_vector_type(8))) short s8v;
typedef __attribute__((ext_vector_type(4))) unsigned short us4;

__device__ __forceinline__ unsigned int cvtpk(float lo, float hi) {
  unsigned int r;
  asm volatile("v_cvt_pk_bf16_f32 %0, %1, %2" : "=v"(r) : "v"(lo), "v"(hi));
  return r;
}

// ---------------- gating: logits -> softmax -> top2 (NO atomics) ----------------
__global__ __launch_bounds__(256) void gating_kernel(
    const float* __restrict__ x, const float* __restrict__ Wg,
    const float* __restrict__ bg, int* __restrict__ sel,
    float* __restrict__ wslot)
{
  __shared__ float wg_lds[NE][DIM];   // 64 KB
  #pragma unroll
  for (int i = 0; i < 16; ++i) {
    int f = threadIdx.x + 256 * i;          // float4 index 0..4095
    int d = f >> 1, ep = (f & 1) * 4;
    float4 w = reinterpret_cast<const float4*>(Wg)[f];
    wg_lds[ep + 0][d] = w.x; wg_lds[ep + 1][d] = w.y;
    wg_lds[ep + 2][d] = w.z; wg_lds[ep + 3][d] = w.w;
  }
  __syncthreads();

  int wave = threadIdx.x >> 6, lane = threadIdx.x & 63;
  #pragma unroll 2
  for (int j = 0; j < 4; ++j) {
    int n = blockIdx.x * 16 + wave * 4 + j;
    const float4* x4 = reinterpret_cast<const float4*>(x + (size_t)n * DIM);
    float acc[NE] = {0.f,0.f,0.f,0.f,0.f,0.f,0.f,0.f};
    #pragma unroll
    for (int i = 0; i < 8; ++i) {
      int d4 = lane + 64 * i;
      float4 xv = x4[d4];
      #pragma unroll
      for (int e = 0; e < NE; ++e) {
        float4 w = *reinterpret_cast<const float4*>(&wg_lds[e][d4 * 4]);
        acc[e] += xv.x * w.x + xv.y * w.y + xv.z * w.z + xv.w * w.w;
      }
    }
    #pragma unroll
    for (int e = 0; e < NE; ++e)
      #pragma unroll
      for (int off = 32; off; off >>= 1)
        acc[e] += __shfl_xor(acc[e], off);

    if (lane == 0) {
      float m = -1e30f;
      #pragma unroll
      for (int e = 0; e < NE; ++e) { acc[e] += bg[e]; m = fmaxf(m, acc[e]); }
      float p[NE]; float s = 0.f;
      #pragma unroll
      for (int e = 0; e < NE; ++e) { p[e] = expf(acc[e] - m); s += p[e]; }
      float inv = 1.0f / s;
      int e1 = 0; float v1 = p[0];
      #pragma unroll
      for (int e = 1; e < NE; ++e) if (p[e] > v1) { v1 = p[e]; e1 = e; }
      int e2 = -1; float v2 = -1.f;
      #pragma unroll
      for (int e = 0; e < NE; ++e) if (e != e1 && p[e] > v2) { v2 = p[e]; e2 = e; }
      sel[n] = e1 | (e2 << 4);
      wslot[n] = v1 * inv;
      wslot[N_TOK + n] = v2 * inv;
    }
  }
}

// ---------------- build per-(slot,expert) token lists: deterministic compaction ----------------
__global__ __launch_bounds__(256) void build_lists_kernel(
    const int* __restrict__ sel, int* __restrict__ counts, int* __restrict__ lists)
{
  __shared__ int wsum[4];
  __shared__ int runbase;
  int b = blockIdx.x;           // 0..15: slot = b>>3, expert = b&7
  int s = b >> 3, e = b & 7;
  int t = threadIdx.x, lane = t & 63, wave = t >> 6;
  if (t == 0) runbase = 0;
  __syncthreads();
  int* listp = lists + (size_t)b * N_TOK;
  for (int base = 0; base < N_TOK; base += 256) {
    int n = base + t;
    int sv = sel[n];
    int field = s ? (sv >> 4) : (sv & 15);
    bool p = (field == e);
    unsigned long long mask = __ballot(p);
    int rank = __popcll(mask & ((1ull << lane) - 1ull));
    int wtot = __popcll(mask);
    if (lane == 0) wsum[wave] = wtot;
    __syncthreads();
    int wbase = 0;
    #pragma unroll
    for (int w = 0; w < 4; ++w) wbase += (w < wave) ? wsum[w] : 0;
    int tot = wsum[0] + wsum[1] + wsum[2] + wsum[3];
    if (p) listp[runbase + wbase + rank] = n;
    __syncthreads();
    if (t == 0) runbase += tot;
    __syncthreads();
  }
  if (t == 0) counts[b] = runbase;
}

// ---------------- build compact tile descriptors ----------------
__global__ void build_desc_kernel(const int* __restrict__ counts,
                                  int* __restrict__ gfirst, int* __restrict__ desc)
{
  if (threadIdx.x == 0 && blockIdx.x == 0) {
    for (int s = 0; s < 2; ++s) {
      int tc = 0;
      for (int e = 0; e < NE; ++e) {
        gfirst[s * 9 + e] = tc;
        int nt = (counts[s * NE + e] + 127) >> 7;
        for (int i = 0; i < nt; ++i) desc[s * 71 + tc++] = (e << 8) | i;
      }
      gfirst[s * 9 + 8] = tc;
    }
  }
}

// ---------------- GEMM: R3 tile/layout/order, re-sharded over 16 waves ----------------
// Each wave owns a 32x32 sub-tile: acc = 2x2 16x16 frags = 16 VGPR.
template <int PHASE>
__global__ __launch_bounds__(1024, 6) void moe_gemm_f32(
    const float* __restrict__ xf, const float* __restrict__ Wef,
    const float* __restrict__ be, const int* __restrict__ counts,
    const int* __restrict__ gfirst, const int* __restrict__ desc,
    const int* __restrict__ lists, const float* __restrict__ wslot,
    float* __restrict__ out)
{
  __shared__ __align__(16) u16 A_lds[128 * 64];   // bf16 [m][k], XOR-swizzled rows
  __shared__ __align__(16) u16 B_lds[128 * 64];   // bf16 [n][k], XOR-swizzled rows
  __shared__ int   tok_lds[128];
  __shared__ float wgt_lds[128];

  const int ntile = blockIdx.x;          // 0..15 (fastest: R3 L2 locality)
  const int idx   = blockIdx.y;          // 0..70
  if (idx >= gfirst[PHASE * 9 + 8]) return;
  const int d  = desc[PHASE * 71 + idx];
  const int e  = d >> 8;
  const int mt = d & 255;
  const int cnt = counts[PHASE * NE + e];

  const int t = threadIdx.x;
  if (t < 128) {
    int r = mt * 128 + t;
    int rc = (r < cnt) ? r : (cnt - 1);
    int tok = lists[(PHASE * NE + e) * N_TOK + rc];
    tok_lds[t] = tok;
    wgt_lds[t] = wslot[PHASE * N_TOK + tok];
  }
  __syncthreads();

  const int lane = t & 63, wid = t >> 6;        // wid 0..15
  const int wm = (wid & 3) * 32, wn = (wid >> 2) * 32;

  f4v acc[2][2];
  f4v zero = {0.f, 0.f, 0.f, 0.f};
  #pragma unroll
  for (int mi = 0; mi < 2; ++mi)
    #pragma unroll
    for (int ni = 0; ni < 2; ++ni) acc[mi][ni] = zero;

  const float* wef = Wef + (size_t)e * DIM * HID;

  // A: 2 float4 per thread (flat = t + 1024*i covers 2048 (row,16B-chunk) slots)
  const float* ap[2]; unsigned int ab[2];
  #pragma unroll
  for (int i = 0; i < 2; ++i) {
    int flat = t + 1024 * i;
    int row = flat >> 4, c4 = flat & 15;
    ap[i] = xf + (size_t)tok_lds[row] * DIM + c4 * 4;
    ab[i] = ((unsigned int)(row * 128 + c4 * 8)) ^ (((unsigned int)row & 7u) << 4);
  }
  // B: 8 scalar column loads per thread (bn = n-col, bh = k-chunk of 8)
  const int bn = t & 127, bh = t >> 7;          // bh 0..7
  const float* bp0 = wef + (size_t)(bh * 8) * HID + ntile * 128 + bn;
  const unsigned int bbyte = ((unsigned int)(bn * 128 + bh * 16)) ^ (((unsigned int)bn & 7u) << 4);

  const int lrow = lane & 15, lkg = lane >> 4;

  #pragma unroll 1
  for (int kt = 0; kt < NKT; ++kt) {
    // ---- stage A (2 float4 -> cvt_pk -> 2 x 8B) ----
    #pragma unroll
    for (int i = 0; i < 2; ++i) {
      float4 v = *reinterpret_cast<const float4*>(ap[i] + kt * 64);
      uint2 w; w.x = cvtpk(v.x, v.y); w.y = cvtpk(v.z, v.w);
      *reinterpret_cast<uint2*>(reinterpret_cast<char*>(A_lds) + ab[i]) = w;
    }
    // ---- stage B (8 scalars -> cvt_pk -> 1 x ds_write_b128) ----
    {
      const float* bpk = bp0 + (size_t)kt * 64 * HID;
      float bv[8];
      #pragma unroll
      for (int j = 0; j < 8; ++j) bv[j] = bpk[(size_t)j * HID];
      union { unsigned int w[4]; s8v v; } ub;
      ub.w[0] = cvtpk(bv[0], bv[1]); ub.w[1] = cvtpk(bv[2], bv[3]);
      ub.w[2] = cvtpk(bv[4], bv[5]); ub.w[3] = cvtpk(bv[6], bv[7]);
      *reinterpret_cast<s8v*>(reinterpret_cast<char*>(B_lds) + bbyte) = ub.v;
    }
    __syncthreads();
    // ---- mma: 2x2 frags x 2 kk2 = 8 MFMA ----
    #pragma unroll
    for (int kk2 = 0; kk2 < 2; ++kk2) {
      s8v a[2], b[2];
      unsigned int koff = (unsigned int)(kk2 * 64 + lkg * 16);
      #pragma unroll
      for (int i = 0; i < 2; ++i) {
        unsigned int arow = (unsigned int)(wm + i * 16 + lrow);
        a[i] = *reinterpret_cast<const s8v*>(
            reinterpret_cast<const char*>(A_lds) + ((arow * 128u + koff) ^ ((arow & 7u) << 4)));
        unsigned int brow = (unsigned int)(wn + i * 16 + lrow);
        b[i] = *reinterpret_cast<const s8v*>(
            reinterpret_cast<const char*>(B_lds) + ((brow * 128u + koff) ^ ((brow & 7u) << 4)));
      }
      #pragma unroll
      for (int mi = 0; mi < 2; ++mi)
        #pragma unroll
        for (int ni = 0; ni < 2; ++ni)
          acc[mi][ni] = __builtin_amdgcn_mfma_f32_16x16x32_bf16(a[mi], b[ni], acc[mi][ni], 0, 0, 0);
    }
    __syncthreads();
  }

  // epilogue: D row=(lane>>4)*4+q (A/m), col=lane&15 (B/n)  [m89-verified]
  const float* bev = be + (size_t)e * HID + ntile * 128;
  #pragma unroll
  for (int ni = 0; ni < 2; ++ni) {
    int col = wn + ni * 16 + (lane & 15);
    float bevv = bev[col];
    #pragma unroll
    for (int mi = 0; mi < 2; ++mi) {
      #pragma unroll
      for (int q = 0; q < 4; ++q) {
        int row = wm + mi * 16 + (lane >> 4) * 4 + q;
        if (mt * 128 + row < cnt) {
          int tok = tok_lds[row];
          float w = wgt_lds[row];
          float v = w * (acc[mi][ni][q] + bevv);
          float* o = out + (size_t)tok * HID + ntile * 128 + col;
          if (PHASE == 0) *o = v; else *o += v;
        }
      }
    }
  }
}

// ---------------- host ----------------
extern "C" void kernel_launch(void* const* d_in, const int* in_sizes, int n_in,
                              void* d_out, int out_size, void* d_ws, size_t ws_size,
                              hipStream_t stream) {
  const float* x  = (const float*)d_in[0];
  const float* Wg = (const float*)d_in[1];
  const float* bg = (const float*)d_in[2];
  const float* We = (const float*)d_in[3];
  const float* be = (const float*)d_in[4];
  float* out = (float*)d_out;
  char* ws = (char*)d_ws;

  int*   counts = (int*)ws;                         // 16 ints @0
  int*   gfirst = (int*)(ws + 64);                  // 18 ints
  int*   desc   = (int*)(ws + 256);                 // 142 ints
  int*   sel    = (int*)(ws + 1024);                // 8192 ints
  float* wslot  = (float*)(ws + 33792);             // 16384 f32
  int*   lists  = (int*)(ws + 99328);               // 2*8*8192 ints -> end 623616

  hipLaunchKernelGGL(gating_kernel, dim3(512), dim3(256), 0, stream,
                     x, Wg, bg, sel, wslot);
  hipLaunchKernelGGL(build_lists_kernel, dim3(16), dim3(256), 0, stream,
                     sel, counts, lists);
  hipLaunchKernelGGL(build_desc_kernel, dim3(1), dim3(64), 0, stream,
                     counts, gfirst, desc);

  dim3 ggrid(16, 71);   // x = ntile fastest: R3 L2 locality
  hipLaunchKernelGGL((moe_gemm_f32<0>), ggrid, dim3(1024), 0, stream,
                     x, We, be, counts, gfirst, desc, lists, wslot, out);
  hipLaunchKernelGGL((moe_gemm_f32<1>), ggrid, dim3(1024), 0, stream,
                     x, We, be, counts, gfirst, desc, lists, wslot, out);
}